// Round 3
// baseline (153.708 us; speedup 1.0000x reference)
//
#include <hip/hip_runtime.h>
#include <hip/hip_bf16.h>

// WeightedDiceLoss on MI355X -- round 10: consecutive-row waves + READ-ONLY
// bf16 LDS ring. R9 post-mortem: barrier pipeline bought ~6%; real stall is
// the stride-4 interleave (8 halo LDS reads + 64 unpack VALU per output row)
// plus 2 lockstep barriers/step. Fix: each wave owns 8 CONSECUTIVE rows; the
// block's whole span [R0-15, R0+47] = 63 rows fits LDS as bf16 (63 KB, 2
// blocks/CU). Ring is loaded once cooperatively, then READ-ONLY: hot loop has
// ZERO barriers, zero publishes, no modulo (slot = row-R0+15, compile-time
// offsets), and zero-filled pad rows make it guard-free. Vertical slide is
// now +-1 row: 3 LDS reads + ~130 VALU per output row (was 9 + ~220).
// Waves free-run -> global loads hoist across steps, DS/VALU/HBM overlap.
// XCD swizzle (bijective, 1024%8==0) co-locates adjacent bands per XCD L2.
//
// input, target: (64,1,512,512) fp32. Output: scalar fp32.
// weight = 1 + 5*|box31(target) - target|; loss = 1 - (2*I+1)/(A+B+1).
//
// Ring layout: row slot = 256 u32; u32 d holds cols (2d, 2d+1) as bf16
// (low 16 = even col). Lane reads its 8 cols as ONE uint4 at dword 4*lane.

#define BATCH 64
#define H     512
#define W     512
#define RBAND 32                      // rows per block (4 waves x 8 rows)
#define RING  63                      // rows R0-15 .. R0+47, no wraparound
#define NBLK  (BATCH * (H / RBAND))   // 1024 blocks

static __device__ __forceinline__ unsigned pack2(float e, float o) {
    __hip_bfloat162 h = __float22bfloat162_rn(make_float2(e, o));
    unsigned u; __builtin_memcpy(&u, &h, 4); return u;
}
static __device__ __forceinline__ float2 unpk(unsigned u) {
    return make_float2(__uint_as_float(u << 16),
                       __uint_as_float(u & 0xffff0000u));
}

__global__ __launch_bounds__(256, 2) void fused_kernel(const float* __restrict__ tgt,
                                                       const float* __restrict__ inp,
                                                       float4* __restrict__ partials) {
    const int tid  = threadIdx.x;
    const int lane = tid & 63;
    const int wv   = tid >> 6;
    // XCD-contiguous work id: blocks g = x, x+8, x+16, ... (same XCD under
    // round-robin dispatch) map to contiguous bands -> halo rows hit XCD L2.
    const int g    = blockIdx.x;
    const int blk  = ((g & 7) << 7) | (g >> 3);   // bijective, 1024 % 8 == 0
    const int band = blk & 15;                    // H/RBAND = 16 bands
    const int b    = blk >> 4;
    const int R0   = band * RBAND;
    const float* timg = tgt + (size_t)b * H * W;
    const float* iimg = inp + (size_t)b * H * W;

    __shared__ __align__(16) unsigned ring[RING * 256];   // 64512 B -> 2 blocks/CU

    const int col0 = lane * 8;               // this lane's 8 columns
    const int ofs  = lane * 4;               // lane's uint4 dword offset in a slot

    // ---- cooperative one-shot load: rows R0-15 .. R0+47 (63 slots) --------
    // Out-of-image rows are written as ZEROS -> hot loop needs no guards
    // (zero padding falls out of the ring contents).
    #pragma unroll
    for (int k = 0; k < 16; ++k) {
        const int idx = 4 * k + wv;          // 0..63
        if (idx < RING) {
            const int row = R0 - 15 + idx;
            float4 v0 = make_float4(0.f, 0.f, 0.f, 0.f), v1 = v0;
            if (row >= 0 && row < H) {
                v0 = *(const float4*)(timg + (size_t)row * W + col0);
                v1 = *(const float4*)(timg + (size_t)row * W + col0 + 4);
            }
            uint4 u;
            u.x = pack2(v0.x, v0.y); u.y = pack2(v0.z, v0.w);
            u.z = pack2(v1.x, v1.y); u.w = pack2(v1.z, v1.w);
            *(uint4*)&ring[idx * 256 + ofs] = u;
        }
    }
    __syncthreads();
    // Ring is READ-ONLY from here until the final reduction.

    // wave-edge masks for the horizontal window (zero padding)
    const float mL1 = (lane >= 1) ? 1.f : 0.f;
    const float mR1 = (lane <= 62) ? 1.f : 0.f;
    const float mL2 = (lane >= 2) ? 1.f : 0.f;
    const float mR2 = (lane <= 61) ? 1.f : 0.f;

    // ---- init vertical sums centered at row R0+8*wv (rows -15..+15) -------
    // Slot of row (R0+8wv-15) is exactly 8*wv.
    const int base = 8 * wv;
    float vr[8];
    #pragma unroll
    for (int k = 0; k < 8; ++k) vr[k] = 0.f;
    #pragma unroll
    for (int jj = 0; jj < 31; ++jj) {
        const uint4 c = *(const uint4*)&ring[(base + jj) * 256 + ofs];
        const float2 e0 = unpk(c.x), e1 = unpk(c.y), e2 = unpk(c.z), e3 = unpk(c.w);
        vr[0] += e0.x; vr[1] += e0.y; vr[2] += e1.x; vr[3] += e1.y;
        vr[4] += e2.x; vr[5] += e2.y; vr[6] += e3.x; vr[7] += e3.y;
    }

    const float inv = 1.0f / 961.0f;
    float aI = 0.f, aA = 0.f, aB = 0.f;

    #pragma unroll
    for (int st = 0; st < 8; ++st) {
        const int h  = R0 + 8 * wv + st;     // this step's output row (< H)
        const int sl = base + st;            // slot of row h-15

        // ---- loads for this step (no barriers -> freely hoistable) -------
        const float4 i0 = *(const float4*)(iimg + (size_t)h * W + col0);
        const float4 i1 = *(const float4*)(iimg + (size_t)h * W + col0 + 4);
        const uint4  tc = *(const uint4*)&ring[(sl + 15) * 256 + ofs]; // row h
        uint4 ua = make_uint4(0u, 0u, 0u, 0u), us = ua;
        if (st < 7) {
            ua = *(const uint4*)&ring[(sl + 31) * 256 + ofs];   // row h+16
            us = *(const uint4*)&ring[sl * 256 + ofs];          // row h-15
        }

        // ---- horizontal window from current vr (verified segment-sum) ----
        const float p1 = vr[0];
        const float p2 = p1 + vr[1];
        const float p3 = p2 + vr[2];
        const float p4 = p3 + vr[3];
        const float p5 = p4 + vr[4];
        const float p6 = p5 + vr[5];
        const float p7 = p6 + vr[6];
        const float s  = p7 + vr[7];
        const float f1 = s - p1, f2 = s - p2, f3 = s - p3, f4 = s - p4;
        const float f5 = s - p5, f6 = s - p6, f7 = s - p7;

        const float sL1 = __shfl_up(s, 1, 64);
        const float sR1 = __shfl_down(s, 1, 64);
        const float g1 = __shfl_up(f1, 2, 64);
        const float g2 = __shfl_up(f2, 2, 64);
        const float g3 = __shfl_up(f3, 2, 64);
        const float g4 = __shfl_up(f4, 2, 64);
        const float g5 = __shfl_up(f5, 2, 64);
        const float g6 = __shfl_up(f6, 2, 64);
        const float g7 = __shfl_up(f7, 2, 64);
        const float q1 = __shfl_down(p1, 2, 64);
        const float q2 = __shfl_down(p2, 2, 64);
        const float q3 = __shfl_down(p3, 2, 64);
        const float q4 = __shfl_down(p4, 2, 64);
        const float q5 = __shfl_down(p5, 2, 64);
        const float q6 = __shfl_down(p6, 2, 64);
        const float q7 = __shfl_down(p7, 2, 64);

        const float S3 = fmaf(mL1, sL1, fmaf(mR1, sR1, s));
        float win[8];
        win[0] = fmaf(mL2, g1, S3);
        win[1] = fmaf(mL2, g2, fmaf(mR2, q1, S3));
        win[2] = fmaf(mL2, g3, fmaf(mR2, q2, S3));
        win[3] = fmaf(mL2, g4, fmaf(mR2, q3, S3));
        win[4] = fmaf(mL2, g5, fmaf(mR2, q4, S3));
        win[5] = fmaf(mL2, g6, fmaf(mR2, q5, S3));
        win[6] = fmaf(mL2, g7, fmaf(mR2, q6, S3));
        win[7] = fmaf(mR2, q7, S3);

        const float2 t0 = unpk(tc.x), t1 = unpk(tc.y), t2 = unpk(tc.z), t3 = unpk(tc.w);
        const float tv[8] = {t0.x, t0.y, t1.x, t1.y, t2.x, t2.y, t3.x, t3.y};
        const float iv[8] = {i0.x, i0.y, i0.z, i0.w, i1.x, i1.y, i1.z, i1.w};

        #pragma unroll
        for (int k = 0; k < 8; ++k) {
            const float wgt = fmaf(5.0f, fabsf(fmaf(win[k], inv, -tv[k])), 1.0f);
            aI += iv[k] * tv[k] * wgt;
            aA += iv[k] * wgt;
            aB += tv[k] * wgt;
        }

        // ---- slide vertical window by one row: += row(h+16) - row(h-15) --
        if (st < 7) {
            const float2 a0 = unpk(ua.x), a1 = unpk(ua.y),
                         a2 = unpk(ua.z), a3 = unpk(ua.w);
            const float2 s0 = unpk(us.x), s1 = unpk(us.y),
                         s2 = unpk(us.z), s3 = unpk(us.w);
            vr[0] += a0.x - s0.x; vr[1] += a0.y - s0.y;
            vr[2] += a1.x - s1.x; vr[3] += a1.y - s1.y;
            vr[4] += a2.x - s2.x; vr[5] += a2.y - s2.y;
            vr[6] += a3.x - s3.x; vr[7] += a3.y - s3.y;
        }
    }

    // ---- wave reduction (64 lanes) ----------------------------------------
    #pragma unroll
    for (int off = 32; off > 0; off >>= 1) {
        aI += __shfl_down(aI, off, 64);
        aA += __shfl_down(aA, off, 64);
        aB += __shfl_down(aB, off, 64);
    }
    // All ring READS must be done before we reuse ring storage for the
    // cross-wave reduction (waves free-run now) -> barrier first.
    __syncthreads();
    float* rf = (float*)ring;
    if (lane == 0) { rf[wv] = aI; rf[8 + wv] = aA; rf[16 + wv] = aB; }
    __syncthreads();
    if (tid == 0) {
        float4 o;
        o.x = rf[0] + rf[1] + rf[2] + rf[3];
        o.y = rf[8] + rf[9] + rf[10] + rf[11];
        o.z = rf[16] + rf[17] + rf[18] + rf[19];
        o.w = 0.f;
        partials[g] = o;
    }
}

// ---------------------------------------------------------------------------
// Reduce NBLK (1024) partials + finalize. One block, 1024 threads (16 waves).
// ---------------------------------------------------------------------------
__global__ __launch_bounds__(1024) void reduce_kernel(const float4* __restrict__ partials,
                                                      float* __restrict__ out) {
    const int tid = threadIdx.x;
    const float4 v = partials[tid];          // exactly 1024 entries
    float aI = v.x, aA = v.y, aB = v.z;
    #pragma unroll
    for (int off = 32; off > 0; off >>= 1) {
        aI += __shfl_down(aI, off, 64);
        aA += __shfl_down(aA, off, 64);
        aB += __shfl_down(aB, off, 64);
    }
    __shared__ float s[3][16];
    const int wvx = tid >> 6, ln = tid & 63;
    if (ln == 0) { s[0][wvx] = aI; s[1][wvx] = aA; s[2][wvx] = aB; }
    __syncthreads();
    if (tid == 0) {
        float I = 0.f, A = 0.f, Bv = 0.f;
        #pragma unroll
        for (int k = 0; k < 16; ++k) { I += s[0][k]; A += s[1][k]; Bv += s[2][k]; }
        out[0] = 1.0f - (2.0f * I + 1.0f) / (A + Bv + 1.0f);
    }
}

extern "C" void kernel_launch(void* const* d_in, const int* in_sizes, int n_in,
                              void* d_out, int out_size, void* d_ws, size_t ws_size,
                              hipStream_t stream) {
    const float* inp = (const float*)d_in[0];   // "input"
    const float* tgt = (const float*)d_in[1];   // "target"
    float* out = (float*)d_out;

    // workspace: [0, NBLK*16) per-block partials (float4); written before read.
    float4* partials = (float4*)d_ws;

    fused_kernel<<<NBLK, 256, 0, stream>>>(tgt, inp, partials);
    reduce_kernel<<<1, 1024, 0, stream>>>(partials, out);
}